// Round 12
// baseline (403.863 us; speedup 1.0000x reference)
//
#include <hip/hip_runtime.h>

// TrendGRU R18: R17 (361us) with the epilogue split into two dataflow phases
// to attack the ~265cy/t bubble (R17 budget: 1693 = 1221 VALU + 207 MFMA +
// 265 bubble). Phase 1 reads ONLY aR/aZ (24 sig-side exp2 + QS rcp + rr/zz,
// all 3 groups) and issues while the last-issued aN chain drains; phase 2
// (aN-dependent tanh + h update) overlaps phase 1's trans tails. aX2 moved
// after MFMA issue (feeds only phase 2). Pure reorder of an identical op set
// -> bit-identical results (absmax must stay 0.001953125 exactly).
// Established model: per-SIMD VALU work is the binding constraint (R11b sum
// test); trans floor = 3 exp2/unit (36/t) + 6 grouped rcp; MFMA floor = 6.

#define GRU_T 512
#define FS 28   // FC LDS row stride in floats (16B-aligned float4 rows)

typedef __attribute__((ext_vector_type(8)))  short bf16x8;
typedef __attribute__((ext_vector_type(16))) float f32x16;
typedef __attribute__((ext_vector_type(2)))  float f32x2;
typedef __attribute__((ext_vector_type(2)))  unsigned uint2v;

__device__ __forceinline__ float bf16hi_f(float v) {   // RNE-to-bf16, as float
    unsigned u = __float_as_uint(v);
    u = (u + 0x7FFFu + ((u >> 16) & 1u)) & 0xFFFF0000u;
    return __uint_as_float(u);
}
__device__ __forceinline__ unsigned bf16_rne(float v) {
    unsigned u = __float_as_uint(v);
    return (u + 0x7FFFu + ((u >> 16) & 1u)) >> 16;
}
// packed RNE f32->bf16: dst = [bf16(lo) | bf16(hi)<<16]
__device__ __forceinline__ unsigned cvt_pk_bf16(float lo, float hi) {
    unsigned r;
    asm("v_cvt_pk_bf16_f32 %0, %1, %2" : "=v"(r) : "v"(lo), "v"(hi));
    return r;
}
__device__ __forceinline__ f32x16 mfma32(bf16x8 a, bf16x8 b, f32x16 c) {
    return __builtin_amdgcn_mfma_f32_32x32x16_bf16(a, b, c, 0, 0, 0);
}

__global__ __launch_bounds__(64) void trend_gru_mfma32(
    const float* __restrict__ x,     // (B, T)
    const float* __restrict__ W_ih,  // (72,)
    const float* __restrict__ b_ih,  // (72,)
    const float* __restrict__ W_hh,  // (72, 24) rows r,z,n
    const float* __restrict__ b_hh,  // (72,)
    const float* __restrict__ fc_w,  // (2, 24)
    const float* __restrict__ fc_b,  // (2,)
    float* __restrict__ out)         // (B, 2)
{
    const int lane = threadIdx.x;
    const int e    = lane & 31;          // element (B-col / C-col)
    const int half = lane >> 5;
    const int elem0 = blockIdx.x * 32;

    __shared__ __align__(16) float Flds[32 * FS];

    const float L2E = 1.4426950408889634f;

    // ---- A fragments: hi-only for all 3 gates (R17-validated) ----
    // A layout: row m = lane&31, k = kstep*16 + (lane>>5)*8 + jj.
    bf16x8 Ahi[3][2];   // [gate][kstep]
#pragma unroll
    for (int g = 0; g < 3; ++g) {
        const float sc = (g == 2) ? 2.0f * L2E : L2E;
        const int m = e;
        const bool valid = m < 24;
        const int R = g * 24 + (valid ? m : 0);
        const float wx = (g < 2 && valid) ? sc * W_ih[R] : 0.0f;
        const float bb = valid ? sc * ((g < 2) ? (b_ih[R] + b_hh[R]) : b_hh[R]) : 0.0f;
        const float wxh = bf16hi_f(wx), bbh = bf16hi_f(bb);
#pragma unroll
        for (int s = 0; s < 2; ++s) {
            bf16x8 fh;
#pragma unroll
            for (int jj = 0; jj < 8; ++jj) {
                const int k = s * 16 + half * 8 + jj;
                float vh = 0.0f;
                if (valid && k < 24) {
                    vh = bf16hi_f(sc * W_hh[R * 24 + k]);
                } else if (valid) {
                    if (k == 24 || k == 25)      vh = wxh;       // Wih_hi*(x_hi,x_lo)
                    else if (k == 26)            vh = wx - wxh;  // Wih_lo*x_hi
                    else if (k == 27)            vh = bbh;       // b_hi*1
                    else if (k == 28)            vh = bb - bbh;  // b_lo*1
                }
                fh[jj] = (short)bf16_rne(vh);
            }
            Ahi[g][s] = fh;
        }
    }

    // ---- per-lane n-gate x-path constants (exact fp32), packed in pairs ----
    // slot s (0..11) -> unit j = (s&3) + 8*(s>>2) + 4*half  (C-layout rows)
    f32x2 wn2[6], bn2[6];
#pragma unroll
    for (int p = 0; p < 6; ++p) {
#pragma unroll
        for (int c = 0; c < 2; ++c) {
            const int s = p * 2 + c;
            const int j = (s & 3) + 8 * (s >> 2) + 4 * half;
            wn2[p][c] = 2.0f * L2E * W_ih[48 + j];
            bn2[p][c] = 2.0f * L2E * b_ih[48 + j];
        }
    }

    const float* xp = x + (size_t)(elem0 + e) * GRU_T;

    f32x2 h2[6];
#pragma unroll
    for (int p = 0; p < 6; ++p) { h2[p].x = 0.0f; h2[p].y = 0.0f; }

    // packed-bf16 h dwords. In LOW lanes Pk holds units: P0=[0,1] P1=[2,3]
    // P2=[8,9] P3=[10,11] P4=[16,17] P5=[18,19]; in HIGH lanes: P0=[4,5]
    // P1=[6,7] P2=[12,13] P3=[14,15] P4=[20,21] P5=[22,23].
    unsigned P0 = 0, P1 = 0, P2 = 0, P3 = 0, P4 = 0, P5 = 0;

    const f32x16 z16 = {0.f,0.f,0.f,0.f,0.f,0.f,0.f,0.f,
                        0.f,0.f,0.f,0.f,0.f,0.f,0.f,0.f};
    const f32x2 one2 = {1.0f, 1.0f};
    const f32x2 m2   = {-2.0f, -2.0f};

    float4 xq = *(const float4*)(xp);
#pragma unroll 1
    for (int t4 = 0; t4 < GRU_T / 4; ++t4) {
        // prefetch next quad early (clamped in-bounds; unused on last iter)
        const int nxt = (t4 < GRU_T / 4 - 1) ? (t4 * 4 + 4) : (GRU_T - 4);
        const float4 xqn = *(const float4*)(xp + nxt);
#pragma unroll
        for (int tt = 0; tt < 4; ++tt) {
            const float xv = (tt == 0) ? xq.x : (tt == 1) ? xq.y
                           : (tt == 2) ? xq.z : xq.w;

            // x-pack for B1 (needed before MFMA)
            const unsigned xy = cvt_pk_bf16(xv, 1.0f);        // k26=x_hi k27=1.0
            const float    xh = __uint_as_float(xy << 16);
            const unsigned xx = cvt_pk_bf16(xv, xv - xh);     // k24=x_hi k25=x_lo

            // ---- B fragments entirely in-register via permlane32_swap ----
            const uint2v r02 = __builtin_amdgcn_permlane32_swap(P0, P2, false, false);
            const uint2v r13 = __builtin_amdgcn_permlane32_swap(P1, P3, false, false);
            uint4 b0q;
            b0q.x = r02.x;  // lo:[0,1]   hi:[8,9]
            b0q.y = r13.x;  // lo:[2,3]   hi:[10,11]
            b0q.z = r02.y;  // lo:[4,5]   hi:[12,13]
            b0q.w = r13.y;  // lo:[6,7]   hi:[14,15]

            const uint2v r44 = __builtin_amdgcn_permlane32_swap(P4, P4, false, false);
            const uint2v r55 = __builtin_amdgcn_permlane32_swap(P5, P5, false, false);
            uint4 b1q;
            b1q.x = P4;      // lo:[16,17]
            b1q.y = P5;      // lo:[18,19]
            b1q.z = r44.y;   // lo:[20,21]
            b1q.w = r55.y;   // lo:[22,23]
            if (half) {      // high lanes carry the x/bias K-stream k24..31
                b1q.x = xx; b1q.y = xy; b1q.z = 0x00003F80u; b1q.w = 0u;
            }
            const bf16x8 B0 = *(const bf16x8*)&b0q;
            const bf16x8 B1 = *(const bf16x8*)&b1q;

            // ---- 6 MFMA: r,z first (phase-1 inputs), n last ----
            f32x16 aR = mfma32(Ahi[0][0], B0, z16);
            aR = mfma32(Ahi[0][1], B1, aR);
            f32x16 aZ = mfma32(Ahi[1][0], B0, z16);
            aZ = mfma32(Ahi[1][1], B1, aZ);
            f32x16 aN = mfma32(Ahi[2][0], B0, z16);
            aN = mfma32(Ahi[2][1], B1, aN);

            // aX2 feeds only phase 2 - compute after MFMA issue (drain cover)
            f32x2 aX2[6];
#pragma unroll
            for (int p = 0; p < 6; ++p) {
                const f32x2 xb = {xv, xv};
                aX2[p] = __builtin_elementwise_fma(wn2[p], xb, bn2[p]);
            }

            // ==== PHASE 1: sigmoid side, all 3 groups (reads aR/aZ only) ===
            // Issues while the aN chain (last-issued) drains.
            f32x2 rr[6], zz[6];
#pragma unroll
            for (int G = 0; G < 3; ++G) {
                f32x2 er0, er1, ez0, ez1;
                er0.x = __builtin_amdgcn_exp2f(-aR[G*4+0]);
                er0.y = __builtin_amdgcn_exp2f(-aR[G*4+1]);
                er1.x = __builtin_amdgcn_exp2f(-aR[G*4+2]);
                er1.y = __builtin_amdgcn_exp2f(-aR[G*4+3]);
                ez0.x = __builtin_amdgcn_exp2f(-aZ[G*4+0]);
                ez0.y = __builtin_amdgcn_exp2f(-aZ[G*4+1]);
                ez1.x = __builtin_amdgcn_exp2f(-aZ[G*4+2]);
                ez1.y = __builtin_amdgcn_exp2f(-aZ[G*4+3]);
                const f32x2 dr0 = er0 + one2, dr1 = er1 + one2;
                const f32x2 dz0 = ez0 + one2, dz1 = ez1 + one2;
                const f32x2 pp0 = dr0 * dz0, pp1 = dr1 * dz1;
                const float  s0 = pp0.x * pp0.y, s1 = pp1.x * pp1.y;
                const float  QS = __builtin_amdgcn_rcpf(s0 * s1);
                const float  Q0 = QS * s1, Q1 = QS * s0;      // 1/s0, 1/s1
                f32x2 qi0, qi1;                                // 1/(dr*dz)
                qi0.x = Q0 * pp0.y; qi0.y = Q0 * pp0.x;
                qi1.x = Q1 * pp1.y; qi1.y = Q1 * pp1.x;
                rr[G*2]   = qi0 * dz0;  rr[G*2+1] = qi1 * dz1; // sig(ar)
                zz[G*2]   = qi0 * dr0;  zz[G*2+1] = qi1 * dr1; // sig(az)
            }

            // ==== PHASE 2: tanh side + h update (reads aN, rr, zz) =========
#pragma unroll
            for (int G = 0; G < 3; ++G) {
                f32x2 an0, an1;
                an0.x = aN[G*4+0]; an0.y = aN[G*4+1];
                an1.x = aN[G*4+2]; an1.y = aN[G*4+3];
                const f32x2 u0 = __builtin_elementwise_fma(rr[G*2],   an0, aX2[G*2]);
                const f32x2 u1 = __builtin_elementwise_fma(rr[G*2+1], an1, aX2[G*2+1]);
                f32x2 ev0, ev1;
                ev0.x = __builtin_amdgcn_exp2f(u0.x); ev0.y = __builtin_amdgcn_exp2f(u0.y);
                ev1.x = __builtin_amdgcn_exp2f(u1.x); ev1.y = __builtin_amdgcn_exp2f(u1.y);
                const f32x2 dv0 = ev0 + one2, dv1 = ev1 + one2;
                const float  t0 = dv0.x * dv0.y, t1 = dv1.x * dv1.y;
                const float  QT = __builtin_amdgcn_rcpf(t0 * t1);
                const float  T0 = QT * t1, T1 = QT * t0;
                f32x2 rv0, rv1;                                // 1/dv
                rv0.x = T0 * dv0.y; rv0.y = T0 * dv0.x;
                rv1.x = T1 * dv1.y; rv1.y = T1 * dv1.x;
                const f32x2 nn0 = __builtin_elementwise_fma(m2, rv0, one2);
                const f32x2 nn1 = __builtin_elementwise_fma(m2, rv1, one2);
                const f32x2 hn0 = __builtin_elementwise_fma(zz[G*2],   h2[G*2]   - nn0, nn0);
                const f32x2 hn1 = __builtin_elementwise_fma(zz[G*2+1], h2[G*2+1] - nn1, nn1);
                h2[G*2] = hn0; h2[G*2+1] = hn1;
                const unsigned pa = cvt_pk_bf16(hn0.x, hn0.y);
                const unsigned pb = cvt_pk_bf16(hn1.x, hn1.y);
                if (G == 0)      { P0 = pa; P1 = pb; }
                else if (G == 1) { P2 = pa; P3 = pb; }
                else             { P4 = pa; P5 = pb; }
            }
        }
        xq = xqn;
    }

    // ---- FC head: h (fp32) -> LDS, lanes 0..31 reduce 24 -> 2 ----
#pragma unroll
    for (int G = 0; G < 3; ++G) {
        float4 f4;
        f4.x = h2[G * 2 + 0].x; f4.y = h2[G * 2 + 0].y;
        f4.z = h2[G * 2 + 1].x; f4.w = h2[G * 2 + 1].y;
        *(float4*)(&Flds[e * FS + G * 8 + half * 4]) = f4;
    }
    if (lane < 32) {
        float o0 = fc_b[0], o1 = fc_b[1];
#pragma unroll
        for (int j = 0; j < 24; ++j) {
            const float hv = Flds[lane * FS + j];
            o0 = fmaf(hv, fc_w[j],      o0);
            o1 = fmaf(hv, fc_w[24 + j], o1);
        }
        float2 o; o.x = o0; o.y = o1;
        *(float2*)(out + (size_t)(elem0 + lane) * 2) = o;
    }
}

extern "C" void kernel_launch(void* const* d_in, const int* in_sizes, int n_in,
                              void* d_out, int out_size, void* d_ws, size_t ws_size,
                              hipStream_t stream) {
    const float* x    = (const float*)d_in[0];
    const float* W_ih = (const float*)d_in[1];
    const float* b_ih = (const float*)d_in[2];
    const float* W_hh = (const float*)d_in[3];
    const float* b_hh = (const float*)d_in[4];
    const float* fc_w = (const float*)d_in[5];
    const float* fc_b = (const float*)d_in[6];
    float* out = (float*)d_out;

    const int B = in_sizes[0] / GRU_T;      // 32768
    const int grid = B / 32;                // 1024 blocks x 1 wave
    trend_gru_mfma32<<<grid, 64, 0, stream>>>(x, W_ih, b_ih, W_hh, b_hh,
                                              fc_w, fc_b, out);
}